// Round 1
// baseline (399.219 us; speedup 1.0000x reference)
//
#include <hip/hip_runtime.h>
#include <stdint.h>

#define BATCH 1024
#define DIM 768

typedef unsigned long long u64;

// ---------------------------------------------------------------------------
// Kernel 1: per-row order-independent positional hash of image_features.
// One wave (64 lanes) per row; 4 waves per 256-thread block.
// Equal rows ALWAYS produce equal hashes (deterministic fn of bits+position);
// hash collisions between unequal rows are filtered by exact verify in k2.
// ---------------------------------------------------------------------------
__global__ __launch_bounds__(256) void hash_kernel(const float* __restrict__ img,
                                                   u64* __restrict__ hashes) {
    const int wave = threadIdx.x >> 6;
    const int lane = threadIdx.x & 63;
    const int row  = blockIdx.x * 4 + wave;
    const float4* rp = (const float4*)(img + (size_t)row * DIM);
    u64 h = 0;
#pragma unroll
    for (int c = 0; c < 3; ++c) {
        float4 v = rp[c * 64 + lane];
        int p = c * 256 + lane * 4;
        u64 b0 = (u64)__float_as_uint(v.x);
        u64 b1 = (u64)__float_as_uint(v.y);
        u64 b2 = (u64)__float_as_uint(v.z);
        u64 b3 = (u64)__float_as_uint(v.w);
        h += (b0 + 0x9E3779B97F4A7C15ULL) * (u64)(2 * p + 1);
        h += (b1 + 0x9E3779B97F4A7C15ULL) * (u64)(2 * p + 3);
        h += (b2 + 0x9E3779B97F4A7C15ULL) * (u64)(2 * p + 5);
        h += (b3 + 0x9E3779B97F4A7C15ULL) * (u64)(2 * p + 7);
    }
#pragma unroll
    for (int m = 32; m; m >>= 1) h += __shfl_xor(h, m, 64);
    if (lane == 0) hashes[row] = h;
}

// ---------------------------------------------------------------------------
// Kernel 2: labels[j] = first i (i<=j) with row i exactly equal to row j.
// Thread per row; scan hashes ascending, exact-verify on hash match.
// ---------------------------------------------------------------------------
__global__ __launch_bounds__(256) void label_kernel(const float* __restrict__ img,
                                                    const u64* __restrict__ hashes,
                                                    int* __restrict__ labels) {
    const int j = blockIdx.x * 256 + threadIdx.x;
    const u64 hj = hashes[j];
    int lbl = j;
    for (int i = 0; i < j; ++i) {
        if (hashes[i] == hj) {
            const float* a = img + (size_t)i * DIM;
            const float* b = img + (size_t)j * DIM;
            bool eq = true;
            for (int d = 0; d < DIM; ++d) {
                if (a[d] != b[d]) { eq = false; break; }
            }
            if (eq) { lbl = i; break; }
        }
    }
    labels[j] = lbl;
}

// ---------------------------------------------------------------------------
// Kernel 3: fused GEMM + log-softmax + label gather.
// Block handles 4 rows x all 1024 cols. Image rows live in registers
// (lane holds 12 floats per row, float4-coalesced layout). Each wave computes
// 256 columns: coalesced float4 loads of the text row, 48 FMAs, 64-lane
// butterfly reduction of the 4 partial dots. Logits tile (4x1024 fp32, 16 KB)
// lives in LDS; phase 2 does per-row max + logsumexp and writes row loss.
// ---------------------------------------------------------------------------
__device__ __forceinline__ float dot12(const float4 a[3], const float4& t0,
                                       const float4& t1, const float4& t2) {
    float s = a[0].x * t0.x + a[0].y * t0.y + a[0].z * t0.z + a[0].w * t0.w;
    s += a[1].x * t1.x + a[1].y * t1.y + a[1].z * t1.z + a[1].w * t1.w;
    s += a[2].x * t2.x + a[2].y * t2.y + a[2].z * t2.z + a[2].w * t2.w;
    return s;
}

__global__ __launch_bounds__(256) void clip_main_kernel(const float* __restrict__ img,
                                                        const float* __restrict__ txt,
                                                        const float* __restrict__ scale_p,
                                                        const int* __restrict__ labels,
                                                        float* __restrict__ row_loss) {
    __shared__ float logits[4 * BATCH];  // 16 KB
    const int wave = threadIdx.x >> 6;
    const int lane = threadIdx.x & 63;
    const int row0 = blockIdx.x * 4;
    const float scale = scale_p[0];

    // Load the block's 4 image rows into registers (every wave loads all 4).
    float4 a[4][3];
#pragma unroll
    for (int r = 0; r < 4; ++r) {
        const float4* rp = (const float4*)(img + (size_t)(row0 + r) * DIM);
#pragma unroll
        for (int c = 0; c < 3; ++c) a[r][c] = rp[c * 64 + lane];
    }

    // Phase 1: wave w computes columns [w*256, w*256+256).
    for (int i = 0; i < 256; ++i) {
        const int col = wave * 256 + i;
        const float4* tp = (const float4*)(txt + (size_t)col * DIM);
        float4 t0 = tp[lane];
        float4 t1 = tp[64 + lane];
        float4 t2 = tp[128 + lane];
        float s0 = dot12(a[0], t0, t1, t2);
        float s1 = dot12(a[1], t0, t1, t2);
        float s2 = dot12(a[2], t0, t1, t2);
        float s3 = dot12(a[3], t0, t1, t2);
#pragma unroll
        for (int m = 32; m; m >>= 1) {
            s0 += __shfl_xor(s0, m, 64);
            s1 += __shfl_xor(s1, m, 64);
            s2 += __shfl_xor(s2, m, 64);
            s3 += __shfl_xor(s3, m, 64);
        }
        if (lane < 4) {
            float v = (lane == 0) ? s0 : (lane == 1) ? s1 : (lane == 2) ? s2 : s3;
            logits[lane * BATCH + col] = scale * v;
        }
    }
    __syncthreads();

    // Phase 2: wave w reduces row w of the tile.
    const int r = wave;
    const int row = row0 + r;
    const float4* lr = (const float4*)&logits[r * BATCH];
    float v[16];
    float m = -INFINITY;
#pragma unroll
    for (int c = 0; c < 4; ++c) {
        float4 f = lr[c * 64 + lane];
        v[4 * c + 0] = f.x; v[4 * c + 1] = f.y; v[4 * c + 2] = f.z; v[4 * c + 3] = f.w;
        m = fmaxf(m, fmaxf(fmaxf(f.x, f.y), fmaxf(f.z, f.w)));
    }
#pragma unroll
    for (int s = 32; s; s >>= 1) m = fmaxf(m, __shfl_xor(m, s, 64));
    float sum = 0.0f;
#pragma unroll
    for (int k = 0; k < 16; ++k) sum += __expf(v[k] - m);
#pragma unroll
    for (int s = 32; s; s >>= 1) sum += __shfl_xor(sum, s, 64);
    if (lane == 0) {
        const int lbl = labels[row];
        const float lv = logits[r * BATCH + lbl];
        row_loss[row] = -(lv - m - __logf(sum));
    }
}

// ---------------------------------------------------------------------------
// Kernel 4: mean over the 1024 per-row losses.
// ---------------------------------------------------------------------------
__global__ __launch_bounds__(256) void reduce_kernel(const float* __restrict__ row_loss,
                                                     float* __restrict__ out) {
    const int tid = threadIdx.x;
    float s = row_loss[tid] + row_loss[tid + 256] + row_loss[tid + 512] + row_loss[tid + 768];
#pragma unroll
    for (int m = 32; m; m >>= 1) s += __shfl_xor(s, m, 64);
    __shared__ float partial[4];
    if ((tid & 63) == 0) partial[tid >> 6] = s;
    __syncthreads();
    if (tid == 0) out[0] = (partial[0] + partial[1] + partial[2] + partial[3]) * (1.0f / BATCH);
}

extern "C" void kernel_launch(void* const* d_in, const int* in_sizes, int n_in,
                              void* d_out, int out_size, void* d_ws, size_t ws_size,
                              hipStream_t stream) {
    const float* img   = (const float*)d_in[0];
    const float* txt   = (const float*)d_in[1];
    const float* scale = (const float*)d_in[2];
    float* out = (float*)d_out;

    // Workspace layout (16 KB total):
    u64* hashes   = (u64*)d_ws;                              // 1024 * 8 = 8 KB
    int* labels   = (int*)((char*)d_ws + 8192);              // 1024 * 4 = 4 KB
    float* rloss  = (float*)((char*)d_ws + 8192 + 4096);     // 1024 * 4 = 4 KB

    hash_kernel<<<256, 256, 0, stream>>>(img, hashes);
    label_kernel<<<4, 256, 0, stream>>>(img, hashes, labels);
    clip_main_kernel<<<256, 256, 0, stream>>>(img, txt, scale, labels, rloss);
    reduce_kernel<<<1, 256, 0, stream>>>(rloss, out);
}

// Round 2
// 181.189 us; speedup vs baseline: 2.2033x; 2.2033x over previous
//
#include <hip/hip_runtime.h>
#include <stdint.h>

#define BATCH 1024
#define DIM 768
#define ROWS 4

typedef unsigned long long u64;

// Workspace layout (bytes):
//   [0]     float acc          — global loss accumulator
//   [4]     int   counter      — blocks-done counter
//   [256..] u64   hashes[1024] — per-row image hashes
#define WS_HASH_OFF 256

// ---------------------------------------------------------------------------
// Kernel 1: per-row positional hash of image_features + zero the accumulator.
// One wave per row; 4 waves per 256-thread block. Equal rows -> equal hashes;
// collisions between unequal rows are filtered by exact verify in clip_main.
// ---------------------------------------------------------------------------
__global__ __launch_bounds__(256) void hash_kernel(const float* __restrict__ img,
                                                   float* __restrict__ acc,
                                                   int* __restrict__ counter,
                                                   u64* __restrict__ hashes) {
    if (blockIdx.x == 0 && threadIdx.x == 0) { *acc = 0.0f; *counter = 0; }
    const int wave = threadIdx.x >> 6;
    const int lane = threadIdx.x & 63;
    const int row  = blockIdx.x * 4 + wave;
    const float4* rp = (const float4*)(img + (size_t)row * DIM);
    u64 h = 0;
#pragma unroll
    for (int c = 0; c < 3; ++c) {
        float4 v = rp[c * 64 + lane];
        int p = c * 256 + lane * 4;
        h += ((u64)__float_as_uint(v.x) + 0x9E3779B97F4A7C15ULL) * (u64)(2 * p + 1);
        h += ((u64)__float_as_uint(v.y) + 0x9E3779B97F4A7C15ULL) * (u64)(2 * p + 3);
        h += ((u64)__float_as_uint(v.z) + 0x9E3779B97F4A7C15ULL) * (u64)(2 * p + 5);
        h += ((u64)__float_as_uint(v.w) + 0x9E3779B97F4A7C15ULL) * (u64)(2 * p + 7);
    }
#pragma unroll
    for (int m = 32; m; m >>= 1) h += __shfl_xor(h, m, 64);
    if (lane == 0) hashes[row] = h;
}

// ---------------------------------------------------------------------------
// Kernel 2: fused labels + GEMM + log-softmax + mean-reduce.
// Grid 256 blocks x 1024 threads (16 waves). Block handles 4 rows x 1024 cols.
// Image rows in registers (a[4][3] float4 per lane, coalesced layout).
// Phase 0: waves 0-3 resolve the duplicate-label for their row via hashes.
// Phase 1: wave w computes columns [w*64, w*64+64), 2 cols per iteration.
// Phase 2: waves 0-3 do per-row max+logsumexp; block partial -> global atomic;
//          last block writes the mean to d_out.
// ---------------------------------------------------------------------------
__device__ __forceinline__ float dot12(const float4 a[3], const float4& t0,
                                       const float4& t1, const float4& t2) {
    float s = a[0].x * t0.x + a[0].y * t0.y + a[0].z * t0.z + a[0].w * t0.w;
    s += a[1].x * t1.x + a[1].y * t1.y + a[1].z * t1.z + a[1].w * t1.w;
    s += a[2].x * t2.x + a[2].y * t2.y + a[2].z * t2.z + a[2].w * t2.w;
    return s;
}

__global__ __launch_bounds__(1024, 4) void clip_main_kernel(
        const float* __restrict__ img, const float* __restrict__ txt,
        const float* __restrict__ scale_p, const u64* __restrict__ hashes,
        float* __restrict__ acc, int* __restrict__ counter,
        float* __restrict__ out) {
    __shared__ float logits[ROWS * BATCH];  // 16 KB
    __shared__ int   labels_s[ROWS];
    __shared__ float rl[ROWS];
    const int tid  = threadIdx.x;
    const int wave = tid >> 6;
    const int lane = tid & 63;
    const int row0 = blockIdx.x * ROWS;
    const float scale = scale_p[0];

    // Every wave holds all 4 image rows in registers (L1-served re-reads).
    float4 a[ROWS][3];
#pragma unroll
    for (int r = 0; r < ROWS; ++r) {
        const float4* rp = (const float4*)(img + (size_t)(row0 + r) * DIM);
#pragma unroll
        for (int c = 0; c < 3; ++c) a[r][c] = rp[c * 64 + lane];
    }

    // ---- Phase 0: duplicate labels (waves 0-3 only, one row each) ----
    if (wave < ROWS) {
        const int j = row0 + wave;
        const u64 hj = hashes[j];
        int cand = BATCH;  // per-lane first hash-matching index (stride 64)
        for (int i = lane; i < j; i += 64)
            if (hashes[i] == hj) { cand = i; break; }
        int label = j;
        for (;;) {
            int m = cand;
#pragma unroll
            for (int s = 32; s; s >>= 1) m = min(m, __shfl_xor(m, s, 64));
            if (m >= j) break;
            // exact verify row m against row j (row j is in registers)
            const float4* rp = (const float4*)(img + (size_t)m * DIM);
            bool eq = true;
#pragma unroll
            for (int c = 0; c < 3; ++c) {
                float4 v = rp[c * 64 + lane];
                eq = eq && (v.x == a[wave][c].x) && (v.y == a[wave][c].y) &&
                     (v.z == a[wave][c].z) && (v.w == a[wave][c].w);
            }
            if (__all(eq)) { label = m; break; }
            if (cand == m) {  // false positive: owning lane advances
                cand = BATCH;
                for (int i = m + 64; i < j; i += 64)
                    if (hashes[i] == hj) { cand = i; break; }
            }
        }
        if (lane == 0) labels_s[wave] = label;
    }

    // ---- Phase 1: wave w computes 64 columns, 2 per iteration ----
    const int c0 = wave * 64;
    for (int i = 0; i < 64; i += 2) {
        float s[2][ROWS];
#pragma unroll
        for (int u = 0; u < 2; ++u) {
            const int col = c0 + i + u;
            const float4* tp = (const float4*)(txt + (size_t)col * DIM);
            float4 t0 = tp[lane];
            float4 t1 = tp[64 + lane];
            float4 t2 = tp[128 + lane];
#pragma unroll
            for (int r = 0; r < ROWS; ++r) s[u][r] = dot12(a[r], t0, t1, t2);
        }
#pragma unroll
        for (int m = 32; m; m >>= 1) {
#pragma unroll
            for (int u = 0; u < 2; ++u)
#pragma unroll
                for (int r = 0; r < ROWS; ++r) s[u][r] += __shfl_xor(s[u][r], m, 64);
        }
        if (lane < 8) {
            const int u = lane >> 2;
            const int r = lane & 3;
            const float v = s[u][r];
            logits[r * BATCH + c0 + i + u] = scale * v;
        }
    }
    __syncthreads();

    // ---- Phase 2: waves 0-3 reduce their row ----
    if (wave < ROWS) {
        const float4* lr = (const float4*)&logits[wave * BATCH];
        float v[16];
        float m = -INFINITY;
#pragma unroll
        for (int c = 0; c < 4; ++c) {
            float4 f = lr[c * 64 + lane];
            v[4 * c + 0] = f.x; v[4 * c + 1] = f.y; v[4 * c + 2] = f.z; v[4 * c + 3] = f.w;
            m = fmaxf(m, fmaxf(fmaxf(f.x, f.y), fmaxf(f.z, f.w)));
        }
#pragma unroll
        for (int s = 32; s; s >>= 1) m = fmaxf(m, __shfl_xor(m, s, 64));
        float sum = 0.0f;
#pragma unroll
        for (int k = 0; k < 16; ++k) sum += __expf(v[k] - m);
#pragma unroll
        for (int s = 32; s; s >>= 1) sum += __shfl_xor(sum, s, 64);
        if (lane == 0) {
            const float lv = logits[wave * BATCH + labels_s[wave]];
            rl[wave] = -(lv - m - __logf(sum));
        }
    }
    __syncthreads();

    // ---- block partial -> global; last block writes the mean ----
    if (tid == 0) {
        const float part = rl[0] + rl[1] + rl[2] + rl[3];
        atomicAdd(acc, part);
        __threadfence();
        const int old = atomicAdd(counter, 1);
        if (old == (int)gridDim.x - 1) {
            __threadfence();
            const float total = *(volatile float*)acc;
            out[0] = total * (1.0f / BATCH);
        }
    }
}

extern "C" void kernel_launch(void* const* d_in, const int* in_sizes, int n_in,
                              void* d_out, int out_size, void* d_ws, size_t ws_size,
                              hipStream_t stream) {
    const float* img   = (const float*)d_in[0];
    const float* txt   = (const float*)d_in[1];
    const float* scale = (const float*)d_in[2];
    float* out = (float*)d_out;

    float* acc    = (float*)d_ws;
    int*   counter = (int*)((char*)d_ws + 4);
    u64*   hashes = (u64*)((char*)d_ws + WS_HASH_OFF);

    hash_kernel<<<256, 256, 0, stream>>>(img, acc, counter, hashes);
    clip_main_kernel<<<256, 1024, 0, stream>>>(img, txt, scale, hashes, acc, counter, out);
}

// Round 3
// 139.549 us; speedup vs baseline: 2.8608x; 1.2984x over previous
//
#include <hip/hip_runtime.h>
#include <stdint.h>

#define BATCH 1024
#define DIM 768
#define ROWS 4

typedef unsigned long long u64;

// Workspace layout (bytes):
//   [0]     float acc          — global loss accumulator
//   [4]     int   counter      — blocks-done counter
//   [256..] u64   hashes[1024] — per-row image hashes
#define WS_HASH_OFF 256

// ---------------------------------------------------------------------------
// Kernel 1: per-row positional hash of image_features + zero the accumulator.
// One wave per row; 4 waves per 256-thread block. Equal rows -> equal hashes;
// collisions between unequal rows are filtered by exact verify in clip_main.
// ---------------------------------------------------------------------------
__global__ __launch_bounds__(256) void hash_kernel(const float* __restrict__ img,
                                                   float* __restrict__ acc,
                                                   int* __restrict__ counter,
                                                   u64* __restrict__ hashes) {
    if (blockIdx.x == 0 && threadIdx.x == 0) { *acc = 0.0f; *counter = 0; }
    const int wave = threadIdx.x >> 6;
    const int lane = threadIdx.x & 63;
    const int row  = blockIdx.x * 4 + wave;
    const float4* rp = (const float4*)(img + (size_t)row * DIM);
    u64 h = 0;
#pragma unroll
    for (int c = 0; c < 3; ++c) {
        float4 v = rp[c * 64 + lane];
        int p = c * 256 + lane * 4;
        h += ((u64)__float_as_uint(v.x) + 0x9E3779B97F4A7C15ULL) * (u64)(2 * p + 1);
        h += ((u64)__float_as_uint(v.y) + 0x9E3779B97F4A7C15ULL) * (u64)(2 * p + 3);
        h += ((u64)__float_as_uint(v.z) + 0x9E3779B97F4A7C15ULL) * (u64)(2 * p + 5);
        h += ((u64)__float_as_uint(v.w) + 0x9E3779B97F4A7C15ULL) * (u64)(2 * p + 7);
    }
#pragma unroll
    for (int m = 32; m; m >>= 1) h += __shfl_xor(h, m, 64);
    if (lane == 0) hashes[row] = h;
}

// ---------------------------------------------------------------------------
// Kernel 2: fused labels + GEMM + log-softmax + mean-reduce.
// Grid 256 blocks x 1024 threads (16 waves). Block handles 4 rows x 1024 cols.
// NOTE: no dynamic indexing into any register array anywhere (scratch-demotion
// was the R1 bottleneck: 82 MB of scratch writes, VALUBusy 16%).
// ---------------------------------------------------------------------------
__global__ __launch_bounds__(1024, 4) void clip_main_kernel(
        const float* __restrict__ img, const float* __restrict__ txt,
        const float* __restrict__ scale_p, const u64* __restrict__ hashes,
        float* __restrict__ acc, int* __restrict__ counter,
        float* __restrict__ out) {
    __shared__ float logits[ROWS * BATCH];  // 16 KB
    __shared__ int   labels_s[ROWS];
    __shared__ float rl[ROWS];
    const int tid  = threadIdx.x;
    const int wave = tid >> 6;
    const int lane = tid & 63;
    const int row0 = blockIdx.x * ROWS;
    const float scale = scale_p[0];

    // Image rows in registers; ONLY compile-time indices touch `a`.
    float4 a[ROWS][3];
#pragma unroll
    for (int r = 0; r < ROWS; ++r) {
        const float4* rp = (const float4*)(img + (size_t)(row0 + r) * DIM);
#pragma unroll
        for (int c = 0; c < 3; ++c) a[r][c] = rp[c * 64 + lane];
    }

    // ---- Phase 0: duplicate labels (waves 0-3, one row each).
    // Verify path re-loads row j from global (L2-hot, rare) so we never
    // index `a` by the runtime `wave` value.
    if (wave < ROWS) {
        const int j = row0 + wave;
        const u64 hj = hashes[j];
        int cand = BATCH;  // per-lane first hash-matching index (stride 64)
        for (int i = lane; i < j; i += 64)
            if (hashes[i] == hj) { cand = i; break; }
        int label = j;
        for (;;) {
            int m = cand;
#pragma unroll
            for (int s = 32; s; s >>= 1) m = min(m, __shfl_xor(m, s, 64));
            if (m >= j) break;
            const float4* rpm = (const float4*)(img + (size_t)m * DIM);
            const float4* rpj = (const float4*)(img + (size_t)j * DIM);
            bool eq = true;
#pragma unroll
            for (int c = 0; c < 3; ++c) {
                float4 vm = rpm[c * 64 + lane];
                float4 vj = rpj[c * 64 + lane];
                eq = eq && (vm.x == vj.x) && (vm.y == vj.y) &&
                     (vm.z == vj.z) && (vm.w == vj.w);
            }
            if (__all(eq)) { label = m; break; }
            if (cand == m) {  // false positive: owning lane advances
                cand = BATCH;
                for (int i = m + 64; i < j; i += 64)
                    if (hashes[i] == hj) { cand = i; break; }
            }
        }
        if (lane == 0) labels_s[wave] = label;
    }

    // ---- Phase 1: wave w computes columns [w*64, w*64+64), 2 per iter ----
    const int c0 = wave * 64;
    for (int i = 0; i < 64; i += 2) {
        float s00, s01, s02, s03, s10, s11, s12, s13;
        {
            const float4* tp = (const float4*)(txt + (size_t)(c0 + i) * DIM);
            float4 t0 = tp[lane];
            float4 t1 = tp[64 + lane];
            float4 t2 = tp[128 + lane];
            s00 = a[0][0].x*t0.x + a[0][0].y*t0.y + a[0][0].z*t0.z + a[0][0].w*t0.w
                + a[0][1].x*t1.x + a[0][1].y*t1.y + a[0][1].z*t1.z + a[0][1].w*t1.w
                + a[0][2].x*t2.x + a[0][2].y*t2.y + a[0][2].z*t2.z + a[0][2].w*t2.w;
            s01 = a[1][0].x*t0.x + a[1][0].y*t0.y + a[1][0].z*t0.z + a[1][0].w*t0.w
                + a[1][1].x*t1.x + a[1][1].y*t1.y + a[1][1].z*t1.z + a[1][1].w*t1.w
                + a[1][2].x*t2.x + a[1][2].y*t2.y + a[1][2].z*t2.z + a[1][2].w*t2.w;
            s02 = a[2][0].x*t0.x + a[2][0].y*t0.y + a[2][0].z*t0.z + a[2][0].w*t0.w
                + a[2][1].x*t1.x + a[2][1].y*t1.y + a[2][1].z*t1.z + a[2][1].w*t1.w
                + a[2][2].x*t2.x + a[2][2].y*t2.y + a[2][2].z*t2.z + a[2][2].w*t2.w;
            s03 = a[3][0].x*t0.x + a[3][0].y*t0.y + a[3][0].z*t0.z + a[3][0].w*t0.w
                + a[3][1].x*t1.x + a[3][1].y*t1.y + a[3][1].z*t1.z + a[3][1].w*t1.w
                + a[3][2].x*t2.x + a[3][2].y*t2.y + a[3][2].z*t2.z + a[3][2].w*t2.w;
        }
        {
            const float4* tp = (const float4*)(txt + (size_t)(c0 + i + 1) * DIM);
            float4 t0 = tp[lane];
            float4 t1 = tp[64 + lane];
            float4 t2 = tp[128 + lane];
            s10 = a[0][0].x*t0.x + a[0][0].y*t0.y + a[0][0].z*t0.z + a[0][0].w*t0.w
                + a[0][1].x*t1.x + a[0][1].y*t1.y + a[0][1].z*t1.z + a[0][1].w*t1.w
                + a[0][2].x*t2.x + a[0][2].y*t2.y + a[0][2].z*t2.z + a[0][2].w*t2.w;
            s11 = a[1][0].x*t0.x + a[1][0].y*t0.y + a[1][0].z*t0.z + a[1][0].w*t0.w
                + a[1][1].x*t1.x + a[1][1].y*t1.y + a[1][1].z*t1.z + a[1][1].w*t1.w
                + a[1][2].x*t2.x + a[1][2].y*t2.y + a[1][2].z*t2.z + a[1][2].w*t2.w;
            s12 = a[2][0].x*t0.x + a[2][0].y*t0.y + a[2][0].z*t0.z + a[2][0].w*t0.w
                + a[2][1].x*t1.x + a[2][1].y*t1.y + a[2][1].z*t1.z + a[2][1].w*t1.w
                + a[2][2].x*t2.x + a[2][2].y*t2.y + a[2][2].z*t2.z + a[2][2].w*t2.w;
            s13 = a[3][0].x*t0.x + a[3][0].y*t0.y + a[3][0].z*t0.z + a[3][0].w*t0.w
                + a[3][1].x*t1.x + a[3][1].y*t1.y + a[3][1].z*t1.z + a[3][1].w*t1.w
                + a[3][2].x*t2.x + a[3][2].y*t2.y + a[3][2].z*t2.z + a[3][2].w*t2.w;
        }
#pragma unroll
        for (int m = 32; m; m >>= 1) {
            s00 += __shfl_xor(s00, m, 64);
            s01 += __shfl_xor(s01, m, 64);
            s02 += __shfl_xor(s02, m, 64);
            s03 += __shfl_xor(s03, m, 64);
            s10 += __shfl_xor(s10, m, 64);
            s11 += __shfl_xor(s11, m, 64);
            s12 += __shfl_xor(s12, m, 64);
            s13 += __shfl_xor(s13, m, 64);
        }
        // All lanes hold all 8 totals; lanes 0-7 select theirs via cndmask
        // chains (compile-time indices only — no scratch demotion).
        float v = s00;
        v = (lane == 1) ? s01 : v;
        v = (lane == 2) ? s02 : v;
        v = (lane == 3) ? s03 : v;
        v = (lane == 4) ? s10 : v;
        v = (lane == 5) ? s11 : v;
        v = (lane == 6) ? s12 : v;
        v = (lane == 7) ? s13 : v;
        if (lane < 8) {
            const int u = lane >> 2;   // which column of the pair
            const int r = lane & 3;    // which row
            logits[r * BATCH + c0 + i + u] = scale * v;
        }
    }
    __syncthreads();

    // ---- Phase 2: waves 0-3 reduce their row ----
    if (wave < ROWS) {
        const float4* lr = (const float4*)&logits[wave * BATCH];
        float v[16];
        float m = -INFINITY;
#pragma unroll
        for (int c = 0; c < 4; ++c) {
            float4 f = lr[c * 64 + lane];
            v[4 * c + 0] = f.x; v[4 * c + 1] = f.y; v[4 * c + 2] = f.z; v[4 * c + 3] = f.w;
            m = fmaxf(m, fmaxf(fmaxf(f.x, f.y), fmaxf(f.z, f.w)));
        }
#pragma unroll
        for (int s = 32; s; s >>= 1) m = fmaxf(m, __shfl_xor(m, s, 64));
        float sum = 0.0f;
#pragma unroll
        for (int k = 0; k < 16; ++k) sum += __expf(v[k] - m);
#pragma unroll
        for (int s = 32; s; s >>= 1) sum += __shfl_xor(sum, s, 64);
        if (lane == 0) {
            const float lv = logits[wave * BATCH + labels_s[wave]];
            rl[wave] = -(lv - m - __logf(sum));
        }
    }
    __syncthreads();

    // ---- block partial -> global; last block writes the mean ----
    if (tid == 0) {
        const float part = rl[0] + rl[1] + rl[2] + rl[3];
        atomicAdd(acc, part);
        __threadfence();
        const int old = atomicAdd(counter, 1);
        if (old == (int)gridDim.x - 1) {
            __threadfence();
            const float total = *(volatile float*)acc;
            out[0] = total * (1.0f / BATCH);
        }
    }
}

extern "C" void kernel_launch(void* const* d_in, const int* in_sizes, int n_in,
                              void* d_out, int out_size, void* d_ws, size_t ws_size,
                              hipStream_t stream) {
    const float* img   = (const float*)d_in[0];
    const float* txt   = (const float*)d_in[1];
    const float* scale = (const float*)d_in[2];
    float* out = (float*)d_out;

    float* acc     = (float*)d_ws;
    int*   counter = (int*)((char*)d_ws + 4);
    u64*   hashes  = (u64*)((char*)d_ws + WS_HASH_OFF);

    hash_kernel<<<256, 256, 0, stream>>>(img, acc, counter, hashes);
    clip_main_kernel<<<256, 1024, 0, stream>>>(img, txt, scale, hashes, acc, counter, out);
}